// Round 1
// baseline (689.157 us; speedup 1.0000x reference)
//
#include <hip/hip_runtime.h>
#include <cstdint>
#include <cstddef>

#define D 64
#define SEQ_LD 192

static __device__ __forceinline__ float sigmoidf_(float x) {
    return 1.f / (1.f + __expf(-x));
}

// ---------------- graph preprocessing ----------------

__global__ void zero_kernel(float* deg, int* cnt, int n) {
    int i = blockIdx.x * blockDim.x + threadIdx.x;
    if (i < n) { deg[i] = 0.f; cnt[i] = 0; }
}

__global__ void count_kernel(const int* __restrict__ src, const int* __restrict__ dst,
                             const float* __restrict__ w, float* deg, int* cnt, int E) {
    int e = blockIdx.x * blockDim.x + threadIdx.x;
    if (e < E) {
        atomicAdd(&deg[src[e]], w[e]);
        atomicAdd(&cnt[dst[e]], 1);
    }
}

__global__ void dinv_kernel(const float* __restrict__ deg, float* dinv, int n) {
    int i = blockIdx.x * blockDim.x + threadIdx.x;
    if (i < n) {
        float d = deg[i];
        dinv[i] = (d > 0.f) ? rsqrtf(d) : 0.f;
    }
}

// scan over cnt -> row_start (exclusive). 1024 elems per block, 256 threads.
__global__ void scan1_kernel(const int* __restrict__ cnt, int* row_start, int* bsum, int n) {
    __shared__ int sd[256];
    int t = threadIdx.x;
    int base = blockIdx.x * 1024 + t * 4;
    int v[4];
    int s = 0;
#pragma unroll
    for (int j = 0; j < 4; j++) {
        int idx = base + j;
        v[j] = (idx < n) ? cnt[idx] : 0;
        s += v[j];
    }
    sd[t] = s;
    __syncthreads();
    for (int off = 1; off < 256; off <<= 1) {
        int add = (t >= off) ? sd[t - off] : 0;
        __syncthreads();
        sd[t] += add;
        __syncthreads();
    }
    int incl = sd[t];
    int excl = incl - s;
    int p = excl;
#pragma unroll
    for (int j = 0; j < 4; j++) {
        int idx = base + j;
        if (idx < n) row_start[idx] = p;
        p += v[j];
    }
    if (t == 255) bsum[blockIdx.x] = incl;
}

__global__ void scan2_kernel(const int* __restrict__ bsum, int* bofs, int nb) {
    if (threadIdx.x == 0 && blockIdx.x == 0) {
        int run = 0;
        for (int i = 0; i < nb; i++) { bofs[i] = run; run += bsum[i]; }
    }
}

__global__ void scan3_kernel(int* row_start, int* cursor, const int* __restrict__ bofs, int n) {
    int i = blockIdx.x * blockDim.x + threadIdx.x;
    if (i < n) {
        int v = row_start[i] + bofs[i >> 10];
        row_start[i] = v;
        cursor[i] = v;
    }
}

__global__ void scatter_kernel(const int* __restrict__ src, const int* __restrict__ dst,
                               const float* __restrict__ w, const float* __restrict__ dinv,
                               int* cursor, int* ssrc, float* snorm, int E) {
    int e = blockIdx.x * blockDim.x + threadIdx.x;
    if (e < E) {
        int s = src[e], d = dst[e];
        float nm = w[e] * dinv[s] * dinv[d];
        int pos = atomicAdd(&cursor[d], 1);
        ssrc[pos] = s;
        snorm[pos] = nm;
    }
}

// ---------------- T-sequence (Chebyshev) ----------------

// copy [N,64] (stride 64) into seq column block (stride 192)
__global__ void copy_to_seq_kernel(const float* __restrict__ in, float* __restrict__ out, int total) {
    int i = blockIdx.x * blockDim.x + threadIdx.x;
    if (i < total) {
        int n = i >> 6, d = i & 63;
        out[(size_t)n * SEQ_LD + d] = in[i];
    }
}

// one wave per node; lane = feature. mode 0: out = (c-1)v - c*A v ; mode 1: out = 2*lhat(v) - w0
__global__ __launch_bounds__(256) void lhat_kernel(
    const float* __restrict__ v, const float* __restrict__ w0, float* __restrict__ out,
    const int* __restrict__ row_start, const int* __restrict__ cnt,
    const int* __restrict__ ssrc, const float* __restrict__ snorm,
    const float* __restrict__ lam_ptr, int mode, int n) {
    int wave = (blockIdx.x * blockDim.x + threadIdx.x) >> 6;
    int lane = threadIdx.x & 63;
    if (wave >= n) return;
    float c = 2.f / lam_ptr[0];
    int e = row_start[wave];
    int end = e + cnt[wave];
    float acc = 0.f, acc2 = 0.f;
    for (; e + 1 < end; e += 2) {
        int s0 = ssrc[e], s1 = ssrc[e + 1];
        float n0 = snorm[e], n1 = snorm[e + 1];
        acc  += n0 * v[(size_t)s0 * SEQ_LD + lane];
        acc2 += n1 * v[(size_t)s1 * SEQ_LD + lane];
    }
    if (e < end) acc += snorm[e] * v[(size_t)ssrc[e] * SEQ_LD + lane];
    acc += acc2;
    size_t o = (size_t)wave * SEQ_LD + lane;
    float lh = (c - 1.f) * v[o] - c * acc;
    out[o] = (mode == 0) ? lh : (2.f * lh - w0[o]);
}

// ---------------- GEMM: [N,192] @ [192, ngates*64] ----------------
// W rows come from conv_w[cg][kt][i][j]; gate = blockIdx.y selects cg.
__global__ __launch_bounds__(256) void gemm_kernel(
    const float* __restrict__ A, const float* __restrict__ convw,
    float* __restrict__ out, int out_ld, int cg0, int cg1, int cg2, int n) {
    __shared__ float As[128][65];
    __shared__ float Ws[64][68];
    int t = threadIdx.x;
    int gate = blockIdx.y;
    int cg = (gate == 0) ? cg0 : ((gate == 1) ? cg1 : cg2);
    int base_row = blockIdx.x * 128;
    int cj = (t & 15) * 4;     // output col within gate block
    int rg = (t >> 4) * 8;     // compute row base
    float acc[8][4];
#pragma unroll
    for (int i = 0; i < 8; i++)
#pragma unroll
        for (int j = 0; j < 4; j++) acc[i][j] = 0.f;

    for (int kt = 0; kt < 3; kt++) {
        // load A tile [128][64]
#pragma unroll
        for (int i = 0; i < 8; i++) {
            int r = (t >> 4) + 16 * i;
            int gr = base_row + r;
            if (gr >= n) gr = n - 1;
            const float4 a4 = *(const float4*)&A[(size_t)gr * SEQ_LD + kt * 64 + ((t & 15) * 4)];
            As[r][(t & 15) * 4 + 0] = a4.x;
            As[r][(t & 15) * 4 + 1] = a4.y;
            As[r][(t & 15) * 4 + 2] = a4.z;
            As[r][(t & 15) * 4 + 3] = a4.w;
        }
        // load W tile [64][64] from conv_w[cg][kt]
        const float* Wp = convw + ((size_t)cg * 3 + kt) * 4096;
#pragma unroll
        for (int i = 0; i < 4; i++) {
            int f = t + 256 * i;
            int kr = f >> 4;
            int c4 = (f & 15) * 4;
            *(float4*)&Ws[kr][c4] = *(const float4*)&Wp[kr * 64 + c4];
        }
        __syncthreads();
        for (int k = 0; k < 64; k++) {
            float4 b = *(const float4*)&Ws[k][cj];
#pragma unroll
            for (int i = 0; i < 8; i++) {
                float a = As[rg + i][k];
                acc[i][0] += a * b.x;
                acc[i][1] += a * b.y;
                acc[i][2] += a * b.z;
                acc[i][3] += a * b.w;
            }
        }
        __syncthreads();
    }
#pragma unroll
    for (int i = 0; i < 8; i++) {
        int gr = base_row + rg + i;
        if (gr < n) {
            float4 o4 = make_float4(acc[i][0], acc[i][1], acc[i][2], acc[i][3]);
            *(float4*)&out[(size_t)gr * out_ld + gate * 64 + cj] = o4;
        }
    }
}

// ---------------- gates ----------------

__global__ void gate_kernel(const float* __restrict__ GX, const float* __restrict__ GH,
                            const float* __restrict__ convb, const float* __restrict__ H,
                            float* __restrict__ Z, float* __restrict__ HR, int total) {
    int i = blockIdx.x * blockDim.x + threadIdx.x;
    if (i < total) {
        int n = i >> 6, d = i & 63;
        float z = sigmoidf_(GX[(size_t)n * SEQ_LD + d] + GH[(size_t)n * 128 + d]
                            + convb[0 * 64 + d] + convb[1 * 64 + d]);
        float r = sigmoidf_(GX[(size_t)n * SEQ_LD + 64 + d] + GH[(size_t)n * 128 + 64 + d]
                            + convb[2 * 64 + d] + convb[3 * 64 + d]);
        Z[i] = z;
        HR[i] = H[i] * r;
    }
}

__global__ void final_kernel(const float* __restrict__ GX, const float* __restrict__ GHR,
                             const float* __restrict__ convb, const float* __restrict__ Z,
                             const float* __restrict__ H, float* __restrict__ out, int total) {
    int i = blockIdx.x * blockDim.x + threadIdx.x;
    if (i < total) {
        int n = i >> 6, d = i & 63;
        float ht = tanhf(GX[(size_t)n * SEQ_LD + 128 + d] + GHR[i]
                         + convb[4 * 64 + d] + convb[5 * 64 + d]);
        float z = Z[i];
        out[i] = z * ht + (1.f - z) * H[i];
    }
}

// ---------------- launch ----------------

extern "C" void kernel_launch(void* const* d_in, const int* in_sizes, int n_in,
                              void* d_out, int out_size, void* d_ws, size_t ws_size,
                              hipStream_t stream) {
    const float* X     = (const float*)d_in[0];
    const int*   ei    = (const int*)d_in[1];
    const float* ew    = (const float*)d_in[2];
    const float* H     = (const float*)d_in[3];
    const float* lam   = (const float*)d_in[4];
    const float* convw = (const float*)d_in[5];
    const float* convb = (const float*)d_in[6];
    float* out = (float*)d_out;

    const int N = in_sizes[0] / D;
    const int E = in_sizes[2];
    const int* src = ei;
    const int* dst = ei + E;

    // workspace carve-up (256B aligned)
    char* p = (char*)d_ws;
    auto alloc = [&](size_t bytes) {
        void* r = (void*)p;
        p += (bytes + 255) & ~(size_t)255;
        return r;
    };
    float* SEQ  = (float*)alloc((size_t)N * SEQ_LD * 4);  // [N,192]
    float* GX   = (float*)alloc((size_t)N * SEQ_LD * 4);  // [N,192]
    float* GH   = (float*)alloc((size_t)N * 128 * 4);     // [N,128]; first 64 cols reused as GHR
    float* Zb   = (float*)alloc((size_t)N * 64 * 4);
    float* HRb  = (float*)alloc((size_t)N * 64 * 4);
    float* deg  = (float*)alloc((size_t)N * 4);
    float* dinv = (float*)alloc((size_t)N * 4);
    int*   cnt  = (int*)alloc((size_t)N * 4);
    int*   row_start = (int*)alloc((size_t)N * 4);
    int*   cursor    = (int*)alloc((size_t)N * 4);
    int*   bsum = (int*)alloc(256 * 4);
    int*   bofs = (int*)alloc(256 * 4);
    int*   ssrc  = (int*)alloc((size_t)E * 4);
    float* snorm = (float*)alloc((size_t)E * 4);

    const int BLK = 256;
    const int gN   = (N + BLK - 1) / BLK;
    const int gE   = (E + BLK - 1) / BLK;
    const int gND  = (N * D + BLK - 1) / BLK;
    const int gWav = (N * 64 + BLK - 1) / BLK;  // wave-per-node kernels: N waves
    const int nb   = (N + 1023) / 1024;

    // --- CSR build + normalization ---
    zero_kernel<<<gN, BLK, 0, stream>>>(deg, cnt, N);
    count_kernel<<<gE, BLK, 0, stream>>>(src, dst, ew, deg, cnt, E);
    dinv_kernel<<<gN, BLK, 0, stream>>>(deg, dinv, N);
    scan1_kernel<<<nb, BLK, 0, stream>>>(cnt, row_start, bsum, N);
    scan2_kernel<<<1, 64, 0, stream>>>(bsum, bofs, nb);
    scan3_kernel<<<gN, BLK, 0, stream>>>(row_start, cursor, bofs, N);
    scatter_kernel<<<gE, BLK, 0, stream>>>(src, dst, ew, dinv, cursor, ssrc, snorm, E);

    const int gemmGx = (N + 127) / 128;

    // --- X sequence -> GX [N,192] for convs {0,2,4} ---
    copy_to_seq_kernel<<<gND, BLK, 0, stream>>>(X, SEQ, N * D);
    lhat_kernel<<<gWav, BLK, 0, stream>>>(SEQ, nullptr, SEQ + 64, row_start, cnt, ssrc, snorm, lam, 0, N);
    lhat_kernel<<<gWav, BLK, 0, stream>>>(SEQ + 64, SEQ, SEQ + 128, row_start, cnt, ssrc, snorm, lam, 1, N);
    gemm_kernel<<<dim3(gemmGx, 3), BLK, 0, stream>>>(SEQ, convw, GX, 192, 0, 2, 4, N);

    // --- H sequence -> GH [N,128] for convs {1,3} ---
    copy_to_seq_kernel<<<gND, BLK, 0, stream>>>(H, SEQ, N * D);
    lhat_kernel<<<gWav, BLK, 0, stream>>>(SEQ, nullptr, SEQ + 64, row_start, cnt, ssrc, snorm, lam, 0, N);
    lhat_kernel<<<gWav, BLK, 0, stream>>>(SEQ + 64, SEQ, SEQ + 128, row_start, cnt, ssrc, snorm, lam, 1, N);
    gemm_kernel<<<dim3(gemmGx, 2), BLK, 0, stream>>>(SEQ, convw, GH, 128, 1, 3, 3, N);

    // --- Z, R gates; HR = H * R ---
    gate_kernel<<<gND, BLK, 0, stream>>>(GX, GH, convb, H, Zb, HRb, N * D);

    // --- HR sequence -> GHR [N,64] for conv {5} (reuse GH buffer) ---
    copy_to_seq_kernel<<<gND, BLK, 0, stream>>>(HRb, SEQ, N * D);
    lhat_kernel<<<gWav, BLK, 0, stream>>>(SEQ, nullptr, SEQ + 64, row_start, cnt, ssrc, snorm, lam, 0, N);
    lhat_kernel<<<gWav, BLK, 0, stream>>>(SEQ + 64, SEQ, SEQ + 128, row_start, cnt, ssrc, snorm, lam, 1, N);
    gemm_kernel<<<dim3(gemmGx, 1), BLK, 0, stream>>>(SEQ, convw, GH, 64, 5, 5, 5, N);

    // --- H_tilde + blend ---
    final_kernel<<<gND, BLK, 0, stream>>>(GX, GH, convb, Zb, H, out, N * D);
}